// Round 2
// baseline (2024.372 us; speedup 1.0000x reference)
//
#include <hip/hip_runtime.h>
#include <hip/hip_bf16.h>

typedef __attribute__((ext_vector_type(8))) short bf16x8;
typedef __attribute__((ext_vector_type(4))) float f32x4;

__device__ __forceinline__ ushort f2bf(float f) {
  union { float f; unsigned u; } v; v.f = f;
  unsigned r = v.u + 0x7fffu + ((v.u >> 16) & 1u);
  return (ushort)(r >> 16);
}

__device__ __forceinline__ void gld_lds16(const ushort* gsrc, ushort* lds) {
  __builtin_amdgcn_global_load_lds((const __attribute__((address_space(1))) void*)gsrc,
                                   (__attribute__((address_space(3))) void*)lds, 16, 0, 0);
}

// ---------------- fp32 -> bf16 elementwise ----------------
__global__ __launch_bounds__(256) void k_f32_to_bf16(
    const float* __restrict__ src, ushort* __restrict__ dst, size_t n4) {
  size_t i = (size_t)blockIdx.x * 256 + threadIdx.x;
  const size_t stride = (size_t)gridDim.x * 256;
  for (; i < n4; i += stride) {
    const float4 v = reinterpret_cast<const float4*>(src)[i];
    ushort4 u;
    u.x = f2bf(v.x); u.y = f2bf(v.y); u.z = f2bf(v.z); u.w = f2bf(v.w);
    reinterpret_cast<ushort4*>(dst)[i] = u;
  }
}

// ---------------- transpose + fp32->bf16 convert ----------------
// src: [B][R][C] fp32  ->  dst: [B][C][R] bf16
__global__ __launch_bounds__(256) void k_transpose_bf16(
    const float* __restrict__ src, ushort* __restrict__ dst, int R, int C) {
  __shared__ ushort tile[64][68];
  const int b = blockIdx.z;
  const size_t mat = (size_t)R * C;
  const float* s = src + (size_t)b * mat;
  ushort* d = dst + (size_t)b * mat;
  const int c0 = blockIdx.x * 64;
  const int r0 = blockIdx.y * 64;
  const int tx = threadIdx.x & 15;
  const int ty = threadIdx.x >> 4;
#pragma unroll
  for (int it = 0; it < 4; ++it) {
    const int r = ty + 16 * it;
    const float4 v = *reinterpret_cast<const float4*>(s + (size_t)(r0 + r) * C + (c0 + tx * 4));
    ushort4 u;
    u.x = f2bf(v.x); u.y = f2bf(v.y); u.z = f2bf(v.z); u.w = f2bf(v.w);
    *reinterpret_cast<ushort4*>(&tile[r][tx * 4]) = u;
  }
  __syncthreads();
#pragma unroll
  for (int it = 0; it < 4; ++it) {
    const int wy = ty + 16 * it;
    ushort4 u;
    u.x = tile[tx * 4 + 0][wy];
    u.y = tile[tx * 4 + 1][wy];
    u.z = tile[tx * 4 + 2][wy];
    u.w = tile[tx * 4 + 3][wy];
    *reinterpret_cast<ushort4*>(d + (size_t)(c0 + wy) * R + (r0 + tx * 4)) = u;
  }
}

#define BM 128
#define BN 128
#define BKE 64

__device__ __forceinline__ void xcd_map(int bid, int RT, int CT, int& r, int& c) {
  if ((RT & 7) == 0) {
    const int xcd = bid & 7, j = bid >> 3;
    r = xcd + 8 * (j / CT);
    c = j % CT;
  } else {
    r = bid / CT; c = bid % CT;
  }
}

__device__ __forceinline__ int expert_of(const int* g, int E, int m0) {
  int e = 0, base = 0;
  while (e < E - 1 && m0 >= base + g[e]) { base += g[e]; ++e; }
  return e;
}

// ---------------- GEMM1 fused (bf16 A path): h = silu(x@w1) * (x@w3) ----------------
__global__ __launch_bounds__(256) void k_gemm1_swiglu_bf(
    const ushort* __restrict__ xb,   // [T][D] bf16
    const ushort* __restrict__ w1t,  // [E][I][D] bf16
    const ushort* __restrict__ w3t,  // [E][I][D] bf16
    const int* __restrict__ g,
    ushort* __restrict__ h,          // [T][I] bf16
    int T, int D, int I, int E) {
  __shared__ ushort As[BM * BKE];
  __shared__ ushort B1s[BN * BKE];
  __shared__ ushort B3s[BN * BKE];

  const int RT = T / BM, CT = I / BN;
  int r, c;
  xcd_map(blockIdx.x, RT, CT, r, c);
  const int m0 = r * BM, n0 = c * BN;

  const int e = expert_of(g, E, m0);
  const ushort* b1p = w1t + (size_t)e * I * D;
  const ushort* b3p = w3t + (size_t)e * I * D;

  const int tid = threadIdx.x;
  const int lane = tid & 63, wave = tid >> 6;
  const int wr = wave >> 1, wc = wave & 1;

  const f32x4 zero = {0.f, 0.f, 0.f, 0.f};
  f32x4 acc1[4][4], acc3[4][4];
#pragma unroll
  for (int m = 0; m < 4; ++m)
#pragma unroll
    for (int n = 0; n < 4; ++n) { acc1[m][n] = zero; acc3[m][n] = zero; }

  const int brow = lane >> 3;
  const int bcol = (lane & 7) * 8;

  const int KT = D / BKE;
  for (int kt = 0; kt < KT; ++kt) {
    const int k0 = kt * BKE;
    __syncthreads();
#pragma unroll
    for (int q = 0; q < 4; ++q) {
      const int chunk = wave * 4 + q;
      const int row8 = chunk * 8 + brow;
      gld_lds16(xb + (size_t)(m0 + row8) * D + k0 + bcol, &As[chunk * 512]);
      gld_lds16(b1p + (size_t)(n0 + row8) * D + k0 + bcol, &B1s[chunk * 512]);
      gld_lds16(b3p + (size_t)(n0 + row8) * D + k0 + bcol, &B3s[chunk * 512]);
    }
    __syncthreads();
#pragma unroll
    for (int kk = 0; kk < 2; ++kk) {
      const int kb = kk * 32 + (lane >> 4) * 8;
      bf16x8 a[4], b1[4], b3[4];
#pragma unroll
      for (int m = 0; m < 4; ++m)
        a[m] = *reinterpret_cast<const bf16x8*>(&As[(wr * 64 + m * 16 + (lane & 15)) * BKE + kb]);
#pragma unroll
      for (int n = 0; n < 4; ++n) {
        b1[n] = *reinterpret_cast<const bf16x8*>(&B1s[(wc * 64 + n * 16 + (lane & 15)) * BKE + kb]);
        b3[n] = *reinterpret_cast<const bf16x8*>(&B3s[(wc * 64 + n * 16 + (lane & 15)) * BKE + kb]);
      }
#pragma unroll
      for (int m = 0; m < 4; ++m)
#pragma unroll
        for (int n = 0; n < 4; ++n) {
          acc1[m][n] = __builtin_amdgcn_mfma_f32_16x16x32_bf16(a[m], b1[n], acc1[m][n], 0, 0, 0);
          acc3[m][n] = __builtin_amdgcn_mfma_f32_16x16x32_bf16(a[m], b3[n], acc3[m][n], 0, 0, 0);
        }
    }
  }
#pragma unroll
  for (int m = 0; m < 4; ++m)
#pragma unroll
    for (int n = 0; n < 4; ++n)
#pragma unroll
      for (int rr = 0; rr < 4; ++rr) {
        const float v1 = acc1[m][n][rr];
        const float v3 = acc3[m][n][rr];
        const float sv = v1 / (1.f + __expf(-v1));
        const int row = m0 + wr * 64 + m * 16 + (lane >> 4) * 4 + rr;
        const int col = n0 + wc * 64 + n * 16 + (lane & 15);
        h[(size_t)row * I + col] = f2bf(sv * v3);
      }
}

// ---------------- GEMM1 fallback (fp32 A, reg-staged) ----------------
__global__ __launch_bounds__(256) void k_gemm1_swiglu(
    const float* __restrict__ x,
    const ushort* __restrict__ w1t,
    const ushort* __restrict__ w3t,
    const int* __restrict__ g,
    ushort* __restrict__ h,
    int T, int D, int I, int E) {
  __shared__ ushort As[BM * BKE];
  __shared__ ushort B1s[BN * BKE];
  __shared__ ushort B3s[BN * BKE];

  const int RT = T / BM, CT = I / BN;
  int r, c;
  xcd_map(blockIdx.x, RT, CT, r, c);
  const int m0 = r * BM, n0 = c * BN;

  const int e = expert_of(g, E, m0);
  const ushort* b1p = w1t + (size_t)e * I * D;
  const ushort* b3p = w3t + (size_t)e * I * D;

  const int tid = threadIdx.x;
  const int lane = tid & 63, wave = tid >> 6;
  const int wr = wave >> 1, wc = wave & 1;

  const f32x4 zero = {0.f, 0.f, 0.f, 0.f};
  f32x4 acc1[4][4], acc3[4][4];
#pragma unroll
  for (int m = 0; m < 4; ++m)
#pragma unroll
    for (int n = 0; n < 4; ++n) { acc1[m][n] = zero; acc3[m][n] = zero; }

  const int arow = tid >> 4;
  const int acol4 = tid & 15;
  const int brow = lane >> 3;
  const int bcol = (lane & 7) * 8;

  const int KT = D / BKE;
  for (int kt = 0; kt < KT; ++kt) {
    const int k0 = kt * BKE;
    __syncthreads();
#pragma unroll
    for (int i = 0; i < 8; ++i) {
      const int rr = arow + 16 * i;
      const float4 v = *reinterpret_cast<const float4*>(x + (size_t)(m0 + rr) * D + k0 + acol4 * 4);
      ushort4 u; u.x = f2bf(v.x); u.y = f2bf(v.y); u.z = f2bf(v.z); u.w = f2bf(v.w);
      *reinterpret_cast<ushort4*>(&As[rr * BKE + acol4 * 4]) = u;
    }
#pragma unroll
    for (int q = 0; q < 4; ++q) {
      const int chunk = wave * 4 + q;
      const int nrow = chunk * 8 + brow;
      gld_lds16(b1p + (size_t)(n0 + nrow) * D + k0 + bcol, &B1s[chunk * 512]);
      gld_lds16(b3p + (size_t)(n0 + nrow) * D + k0 + bcol, &B3s[chunk * 512]);
    }
    __syncthreads();
#pragma unroll
    for (int kk = 0; kk < 2; ++kk) {
      const int kb = kk * 32 + (lane >> 4) * 8;
      bf16x8 a[4], b1[4], b3[4];
#pragma unroll
      for (int m = 0; m < 4; ++m)
        a[m] = *reinterpret_cast<const bf16x8*>(&As[(wr * 64 + m * 16 + (lane & 15)) * BKE + kb]);
#pragma unroll
      for (int n = 0; n < 4; ++n) {
        b1[n] = *reinterpret_cast<const bf16x8*>(&B1s[(wc * 64 + n * 16 + (lane & 15)) * BKE + kb]);
        b3[n] = *reinterpret_cast<const bf16x8*>(&B3s[(wc * 64 + n * 16 + (lane & 15)) * BKE + kb]);
      }
#pragma unroll
      for (int m = 0; m < 4; ++m)
#pragma unroll
        for (int n = 0; n < 4; ++n) {
          acc1[m][n] = __builtin_amdgcn_mfma_f32_16x16x32_bf16(a[m], b1[n], acc1[m][n], 0, 0, 0);
          acc3[m][n] = __builtin_amdgcn_mfma_f32_16x16x32_bf16(a[m], b3[n], acc3[m][n], 0, 0, 0);
        }
    }
  }
#pragma unroll
  for (int m = 0; m < 4; ++m)
#pragma unroll
    for (int n = 0; n < 4; ++n)
#pragma unroll
      for (int rr = 0; rr < 4; ++rr) {
        const float v1 = acc1[m][n][rr];
        const float v3 = acc3[m][n][rr];
        const float sv = v1 / (1.f + __expf(-v1));
        const int row = m0 + wr * 64 + m * 16 + (lane >> 4) * 4 + rr;
        const int col = n0 + wc * 64 + n * 16 + (lane & 15);
        h[(size_t)row * I + col] = f2bf(sv * v3);
      }
}

// ---------------- GEMM2: out = h @ w2, fp32 out ----------------
__global__ __launch_bounds__(256) void k_gemm2(
    const ushort* __restrict__ h,
    const ushort* __restrict__ w2t,  // [E][D][I] bf16
    const int* __restrict__ g,
    float* __restrict__ out,
    int T, int D, int I, int E) {
  __shared__ ushort As[BM * BKE];
  __shared__ ushort Bs[BN * BKE];

  const int RT = T / BM, CT = D / BN;
  int r, c;
  xcd_map(blockIdx.x, RT, CT, r, c);
  const int m0 = r * BM, n0 = c * BN;

  const int e = expert_of(g, E, m0);
  const ushort* bp = w2t + (size_t)e * D * I;

  const int tid = threadIdx.x;
  const int lane = tid & 63, wave = tid >> 6;
  const int wr = wave >> 1, wc = wave & 1;

  const f32x4 zero = {0.f, 0.f, 0.f, 0.f};
  f32x4 acc[4][4];
#pragma unroll
  for (int m = 0; m < 4; ++m)
#pragma unroll
    for (int n = 0; n < 4; ++n) acc[m][n] = zero;

  const int brow = lane >> 3;
  const int bcol = (lane & 7) * 8;

  const int KT = I / BKE;
  for (int kt = 0; kt < KT; ++kt) {
    const int k0 = kt * BKE;
    __syncthreads();
#pragma unroll
    for (int q = 0; q < 4; ++q) {
      const int chunk = wave * 4 + q;
      const int row8 = chunk * 8 + brow;
      gld_lds16(h + (size_t)(m0 + row8) * I + k0 + bcol, &As[chunk * 512]);
      gld_lds16(bp + (size_t)(n0 + row8) * I + k0 + bcol, &Bs[chunk * 512]);
    }
    __syncthreads();
#pragma unroll
    for (int kk = 0; kk < 2; ++kk) {
      const int kb = kk * 32 + (lane >> 4) * 8;
      bf16x8 a[4], b[4];
#pragma unroll
      for (int m = 0; m < 4; ++m)
        a[m] = *reinterpret_cast<const bf16x8*>(&As[(wr * 64 + m * 16 + (lane & 15)) * BKE + kb]);
#pragma unroll
      for (int n = 0; n < 4; ++n)
        b[n] = *reinterpret_cast<const bf16x8*>(&Bs[(wc * 64 + n * 16 + (lane & 15)) * BKE + kb]);
#pragma unroll
      for (int m = 0; m < 4; ++m)
#pragma unroll
        for (int n = 0; n < 4; ++n)
          acc[m][n] = __builtin_amdgcn_mfma_f32_16x16x32_bf16(a[m], b[n], acc[m][n], 0, 0, 0);
    }
  }
#pragma unroll
  for (int m = 0; m < 4; ++m)
#pragma unroll
    for (int n = 0; n < 4; ++n)
#pragma unroll
      for (int rr = 0; rr < 4; ++rr) {
        const int row = m0 + wr * 64 + m * 16 + (lane >> 4) * 4 + rr;
        const int col = n0 + wc * 64 + n * 16 + (lane & 15);
        out[(size_t)row * D + col] = acc[m][n][rr];
      }
}

// ---------------- launch ----------------
extern "C" void kernel_launch(void* const* d_in, const int* in_sizes, int n_in,
                              void* d_out, int out_size, void* d_ws, size_t ws_size,
                              hipStream_t stream) {
  const float* x  = (const float*)d_in[0];
  const float* w1 = (const float*)d_in[1];
  const float* w2 = (const float*)d_in[2];
  const float* w3 = (const float*)d_in[3];
  const int*   g  = (const int*)d_in[4];

  const int E = in_sizes[4];
  const int D = 4096;
  const int I = 1024;
  const int T = in_sizes[0] / D;

  const size_t szW = (size_t)E * D * I * sizeof(ushort);  // 64 MB
  const size_t szH = (size_t)T * I * sizeof(ushort);      // 64 MB
  const size_t szX = (size_t)T * D * sizeof(ushort);      // 256 MB
  const size_t needSmall = 2 * szW + szH;                 // 192 MB
  const size_t needBig = needSmall + szX;                 // 448 MB
  if (ws_size < needSmall) return;

  char* ws = (char*)d_ws;
  ushort* w1t = (ushort*)ws;              // slot 0 (reused by w2t)
  ushort* w3t = (ushort*)(ws + szW);      // slot 1
  ushort* h   = (ushort*)(ws + 2 * szW);  // slot 2
  ushort* w2t = w1t;
  ushort* xb  = (ushort*)(ws + 2 * szW + szH);  // slot 3 (big path only)

  float* out = (float*)d_out;
  dim3 blk(256);

  k_transpose_bf16<<<dim3(I / 64, D / 64, E), blk, 0, stream>>>(w1, w1t, D, I);
  k_transpose_bf16<<<dim3(I / 64, D / 64, E), blk, 0, stream>>>(w3, w3t, D, I);

  if (ws_size >= needBig) {
    k_f32_to_bf16<<<dim3(2048), blk, 0, stream>>>(x, xb, (size_t)T * D / 4);
    k_gemm1_swiglu_bf<<<dim3((T / BM) * (I / BN)), blk, 0, stream>>>(xb, w1t, w3t, g, h, T, D, I, E);
  } else {
    k_gemm1_swiglu<<<dim3((T / BM) * (I / BN)), blk, 0, stream>>>(x, w1t, w3t, g, h, T, D, I, E);
  }

  k_transpose_bf16<<<dim3(D / 64, I / 64, E), blk, 0, stream>>>(w2, w2t, I, D);

  k_gemm2<<<dim3((T / BM) * (D / BN)), blk, 0, stream>>>(h, w2t, g, out, T, D, I, E);
}

// Round 3
// 1402.113 us; speedup vs baseline: 1.4438x; 1.4438x over previous
//
#include <hip/hip_runtime.h>
#include <hip/hip_bf16.h>

typedef __attribute__((ext_vector_type(8))) short bf16x8;
typedef __attribute__((ext_vector_type(4))) float f32x4;

__device__ __forceinline__ ushort f2bf(float f) {
  union { float f; unsigned u; } v; v.f = f;
  unsigned r = v.u + 0x7fffu + ((v.u >> 16) & 1u);
  return (ushort)(r >> 16);
}

__device__ __forceinline__ void gld_lds16(const ushort* gsrc, ushort* lds) {
  __builtin_amdgcn_global_load_lds((const __attribute__((address_space(1))) void*)gsrc,
                                   (__attribute__((address_space(3))) void*)lds, 16, 0, 0);
}

// ---------------- fp32 -> bf16 elementwise ----------------
__global__ __launch_bounds__(256) void k_f32_to_bf16(
    const float* __restrict__ src, ushort* __restrict__ dst, size_t n4) {
  size_t i = (size_t)blockIdx.x * 256 + threadIdx.x;
  const size_t stride = (size_t)gridDim.x * 256;
  for (; i < n4; i += stride) {
    const float4 v = reinterpret_cast<const float4*>(src)[i];
    ushort4 u;
    u.x = f2bf(v.x); u.y = f2bf(v.y); u.z = f2bf(v.z); u.w = f2bf(v.w);
    reinterpret_cast<ushort4*>(dst)[i] = u;
  }
}

// ---------------- transpose + fp32->bf16 convert ----------------
// src: [B][R][C] fp32  ->  dst: [B][C][R] bf16
__global__ __launch_bounds__(256) void k_transpose_bf16(
    const float* __restrict__ src, ushort* __restrict__ dst, int R, int C) {
  __shared__ ushort tile[64][68];
  const int b = blockIdx.z;
  const size_t mat = (size_t)R * C;
  const float* s = src + (size_t)b * mat;
  ushort* d = dst + (size_t)b * mat;
  const int c0 = blockIdx.x * 64;
  const int r0 = blockIdx.y * 64;
  const int tx = threadIdx.x & 15;
  const int ty = threadIdx.x >> 4;
#pragma unroll
  for (int it = 0; it < 4; ++it) {
    const int r = ty + 16 * it;
    const float4 v = *reinterpret_cast<const float4*>(s + (size_t)(r0 + r) * C + (c0 + tx * 4));
    ushort4 u;
    u.x = f2bf(v.x); u.y = f2bf(v.y); u.z = f2bf(v.z); u.w = f2bf(v.w);
    *reinterpret_cast<ushort4*>(&tile[r][tx * 4]) = u;
  }
  __syncthreads();
#pragma unroll
  for (int it = 0; it < 4; ++it) {
    const int wy = ty + 16 * it;
    ushort4 u;
    u.x = tile[tx * 4 + 0][wy];
    u.y = tile[tx * 4 + 1][wy];
    u.z = tile[tx * 4 + 2][wy];
    u.w = tile[tx * 4 + 3][wy];
    *reinterpret_cast<ushort4*>(d + (size_t)(c0 + wy) * R + (r0 + tx * 4)) = u;
  }
}

#define BM 128
#define BN 128
#define BKE 64

__device__ __forceinline__ void xcd_map(int bid, int RT, int CT, int& r, int& c) {
  if ((RT & 7) == 0) {
    const int xcd = bid & 7, j = bid >> 3;
    r = xcd + 8 * (j / CT);
    c = j % CT;
  } else {
    r = bid / CT; c = bid % CT;
  }
}

__device__ __forceinline__ int expert_of(const int* g, int E, int m0) {
  int e = 0, base = 0;
  while (e < E - 1 && m0 >= base + g[e]) { base += g[e]; ++e; }
  return e;
}

// ---------------- GEMM1 fused, 128x64 tile, 3 blocks/CU ----------------
// h = silu(x@w1) * (x@w3); acc1+acc3 = 64 regs/lane (was 128 -> 1 block/CU)
__global__ __launch_bounds__(256, 3) void k_gemm1_swiglu64(
    const ushort* __restrict__ xb,   // [T][D] bf16
    const ushort* __restrict__ w1t,  // [E][I][D] bf16
    const ushort* __restrict__ w3t,  // [E][I][D] bf16
    const int* __restrict__ g,
    ushort* __restrict__ h,          // [T][I] bf16
    int T, int D, int I, int E) {
  __shared__ ushort As[128 * BKE];   // 16 KB
  __shared__ ushort B1s[64 * BKE];   // 8 KB
  __shared__ ushort B3s[64 * BKE];   // 8 KB

  const int RT = T / 128, CT = I / 64;
  int r, c;
  xcd_map(blockIdx.x, RT, CT, r, c);
  const int m0 = r * 128, n0 = c * 64;

  const int e = expert_of(g, E, m0);
  const ushort* b1p = w1t + (size_t)e * I * D;
  const ushort* b3p = w3t + (size_t)e * I * D;

  const int tid = threadIdx.x;
  const int lane = tid & 63, wave = tid >> 6;
  const int wr = wave >> 1, wc = wave & 1;  // wave tile: rows wr*64, cols wc*32

  const f32x4 zero = {0.f, 0.f, 0.f, 0.f};
  f32x4 acc1[4][2], acc3[4][2];
#pragma unroll
  for (int m = 0; m < 4; ++m)
#pragma unroll
    for (int n = 0; n < 2; ++n) { acc1[m][n] = zero; acc3[m][n] = zero; }

  // staging coords: thread covers 16B (8 cols); 32 rows per 256-thread pass
  const int sr = tid >> 3;         // 0..31
  const int sc = (tid & 7) * 8;    // col element 0..56

  const int KT = D / BKE;
  for (int kt = 0; kt < KT; ++kt) {
    const int k0 = kt * BKE;
    __syncthreads();
    // A: 128 rows, 4 passes
#pragma unroll
    for (int i = 0; i < 4; ++i) {
      const int row = i * 32 + sr;
      gld_lds16(xb + (size_t)(m0 + row) * D + k0 + sc, &As[row * BKE + sc]);
    }
    // B1/B3: 64 rows, 2 passes each
#pragma unroll
    for (int i = 0; i < 2; ++i) {
      const int row = i * 32 + sr;
      gld_lds16(b1p + (size_t)(n0 + row) * D + k0 + sc, &B1s[row * BKE + sc]);
      gld_lds16(b3p + (size_t)(n0 + row) * D + k0 + sc, &B3s[row * BKE + sc]);
    }
    __syncthreads();
#pragma unroll
    for (int kk = 0; kk < 2; ++kk) {
      const int kb = kk * 32 + (lane >> 4) * 8;
      bf16x8 a[4], b1[2], b3[2];
#pragma unroll
      for (int m = 0; m < 4; ++m)
        a[m] = *reinterpret_cast<const bf16x8*>(&As[(wr * 64 + m * 16 + (lane & 15)) * BKE + kb]);
#pragma unroll
      for (int n = 0; n < 2; ++n) {
        b1[n] = *reinterpret_cast<const bf16x8*>(&B1s[(wc * 32 + n * 16 + (lane & 15)) * BKE + kb]);
        b3[n] = *reinterpret_cast<const bf16x8*>(&B3s[(wc * 32 + n * 16 + (lane & 15)) * BKE + kb]);
      }
#pragma unroll
      for (int m = 0; m < 4; ++m)
#pragma unroll
        for (int n = 0; n < 2; ++n) {
          acc1[m][n] = __builtin_amdgcn_mfma_f32_16x16x32_bf16(a[m], b1[n], acc1[m][n], 0, 0, 0);
          acc3[m][n] = __builtin_amdgcn_mfma_f32_16x16x32_bf16(a[m], b3[n], acc3[m][n], 0, 0, 0);
        }
    }
  }
#pragma unroll
  for (int m = 0; m < 4; ++m)
#pragma unroll
    for (int n = 0; n < 2; ++n)
#pragma unroll
      for (int rr = 0; rr < 4; ++rr) {
        const float v1 = acc1[m][n][rr];
        const float v3 = acc3[m][n][rr];
        const float sv = v1 / (1.f + __expf(-v1));
        const int row = m0 + wr * 64 + m * 16 + (lane >> 4) * 4 + rr;
        const int col = n0 + wc * 32 + n * 16 + (lane & 15);
        h[(size_t)row * I + col] = f2bf(sv * v3);
      }
}

// ---------------- GEMM1 fallback (fp32 A, reg-staged, 128x128) ----------------
__global__ __launch_bounds__(256) void k_gemm1_swiglu(
    const float* __restrict__ x,
    const ushort* __restrict__ w1t,
    const ushort* __restrict__ w3t,
    const int* __restrict__ g,
    ushort* __restrict__ h,
    int T, int D, int I, int E) {
  __shared__ ushort As[BM * BKE];
  __shared__ ushort B1s[BN * BKE];
  __shared__ ushort B3s[BN * BKE];

  const int RT = T / BM, CT = I / BN;
  int r, c;
  xcd_map(blockIdx.x, RT, CT, r, c);
  const int m0 = r * BM, n0 = c * BN;

  const int e = expert_of(g, E, m0);
  const ushort* b1p = w1t + (size_t)e * I * D;
  const ushort* b3p = w3t + (size_t)e * I * D;

  const int tid = threadIdx.x;
  const int lane = tid & 63, wave = tid >> 6;
  const int wr = wave >> 1, wc = wave & 1;

  const f32x4 zero = {0.f, 0.f, 0.f, 0.f};
  f32x4 acc1[4][4], acc3[4][4];
#pragma unroll
  for (int m = 0; m < 4; ++m)
#pragma unroll
    for (int n = 0; n < 4; ++n) { acc1[m][n] = zero; acc3[m][n] = zero; }

  const int arow = tid >> 4;
  const int acol4 = tid & 15;
  const int brow = lane >> 3;
  const int bcol = (lane & 7) * 8;

  const int KT = D / BKE;
  for (int kt = 0; kt < KT; ++kt) {
    const int k0 = kt * BKE;
    __syncthreads();
#pragma unroll
    for (int i = 0; i < 8; ++i) {
      const int rr = arow + 16 * i;
      const float4 v = *reinterpret_cast<const float4*>(x + (size_t)(m0 + rr) * D + k0 + acol4 * 4);
      ushort4 u; u.x = f2bf(v.x); u.y = f2bf(v.y); u.z = f2bf(v.z); u.w = f2bf(v.w);
      *reinterpret_cast<ushort4*>(&As[rr * BKE + acol4 * 4]) = u;
    }
#pragma unroll
    for (int q = 0; q < 4; ++q) {
      const int chunk = wave * 4 + q;
      const int nrow = chunk * 8 + brow;
      gld_lds16(b1p + (size_t)(n0 + nrow) * D + k0 + bcol, &B1s[chunk * 512]);
      gld_lds16(b3p + (size_t)(n0 + nrow) * D + k0 + bcol, &B3s[chunk * 512]);
    }
    __syncthreads();
#pragma unroll
    for (int kk = 0; kk < 2; ++kk) {
      const int kb = kk * 32 + (lane >> 4) * 8;
      bf16x8 a[4], b1[4], b3[4];
#pragma unroll
      for (int m = 0; m < 4; ++m)
        a[m] = *reinterpret_cast<const bf16x8*>(&As[(wr * 64 + m * 16 + (lane & 15)) * BKE + kb]);
#pragma unroll
      for (int n = 0; n < 4; ++n) {
        b1[n] = *reinterpret_cast<const bf16x8*>(&B1s[(wc * 64 + n * 16 + (lane & 15)) * BKE + kb]);
        b3[n] = *reinterpret_cast<const bf16x8*>(&B3s[(wc * 64 + n * 16 + (lane & 15)) * BKE + kb]);
      }
#pragma unroll
      for (int m = 0; m < 4; ++m)
#pragma unroll
        for (int n = 0; n < 4; ++n) {
          acc1[m][n] = __builtin_amdgcn_mfma_f32_16x16x32_bf16(a[m], b1[n], acc1[m][n], 0, 0, 0);
          acc3[m][n] = __builtin_amdgcn_mfma_f32_16x16x32_bf16(a[m], b3[n], acc3[m][n], 0, 0, 0);
        }
    }
  }
#pragma unroll
  for (int m = 0; m < 4; ++m)
#pragma unroll
    for (int n = 0; n < 4; ++n)
#pragma unroll
      for (int rr = 0; rr < 4; ++rr) {
        const float v1 = acc1[m][n][rr];
        const float v3 = acc3[m][n][rr];
        const float sv = v1 / (1.f + __expf(-v1));
        const int row = m0 + wr * 64 + m * 16 + (lane >> 4) * 4 + rr;
        const int col = n0 + wc * 64 + n * 16 + (lane & 15);
        h[(size_t)row * I + col] = f2bf(sv * v3);
      }
}

// ---------------- GEMM2: out = h @ w2, fp32 out ----------------
__global__ __launch_bounds__(256) void k_gemm2(
    const ushort* __restrict__ h,
    const ushort* __restrict__ w2t,  // [E][D][I] bf16
    const int* __restrict__ g,
    float* __restrict__ out,
    int T, int D, int I, int E) {
  __shared__ ushort As[BM * BKE];
  __shared__ ushort Bs[BN * BKE];

  const int RT = T / BM, CT = D / BN;
  int r, c;
  xcd_map(blockIdx.x, RT, CT, r, c);
  const int m0 = r * BM, n0 = c * BN;

  const int e = expert_of(g, E, m0);
  const ushort* bp = w2t + (size_t)e * D * I;

  const int tid = threadIdx.x;
  const int lane = tid & 63, wave = tid >> 6;
  const int wr = wave >> 1, wc = wave & 1;

  const f32x4 zero = {0.f, 0.f, 0.f, 0.f};
  f32x4 acc[4][4];
#pragma unroll
  for (int m = 0; m < 4; ++m)
#pragma unroll
    for (int n = 0; n < 4; ++n) acc[m][n] = zero;

  const int brow = lane >> 3;
  const int bcol = (lane & 7) * 8;

  const int KT = I / BKE;
  for (int kt = 0; kt < KT; ++kt) {
    const int k0 = kt * BKE;
    __syncthreads();
#pragma unroll
    for (int q = 0; q < 4; ++q) {
      const int chunk = wave * 4 + q;
      const int row8 = chunk * 8 + brow;
      gld_lds16(h + (size_t)(m0 + row8) * I + k0 + bcol, &As[chunk * 512]);
      gld_lds16(bp + (size_t)(n0 + row8) * I + k0 + bcol, &Bs[chunk * 512]);
    }
    __syncthreads();
#pragma unroll
    for (int kk = 0; kk < 2; ++kk) {
      const int kb = kk * 32 + (lane >> 4) * 8;
      bf16x8 a[4], b[4];
#pragma unroll
      for (int m = 0; m < 4; ++m)
        a[m] = *reinterpret_cast<const bf16x8*>(&As[(wr * 64 + m * 16 + (lane & 15)) * BKE + kb]);
#pragma unroll
      for (int n = 0; n < 4; ++n)
        b[n] = *reinterpret_cast<const bf16x8*>(&Bs[(wc * 64 + n * 16 + (lane & 15)) * BKE + kb]);
#pragma unroll
      for (int m = 0; m < 4; ++m)
#pragma unroll
        for (int n = 0; n < 4; ++n)
          acc[m][n] = __builtin_amdgcn_mfma_f32_16x16x32_bf16(a[m], b[n], acc[m][n], 0, 0, 0);
    }
  }
#pragma unroll
  for (int m = 0; m < 4; ++m)
#pragma unroll
    for (int n = 0; n < 4; ++n)
#pragma unroll
      for (int rr = 0; rr < 4; ++rr) {
        const int row = m0 + wr * 64 + m * 16 + (lane >> 4) * 4 + rr;
        const int col = n0 + wc * 64 + n * 16 + (lane & 15);
        out[(size_t)row * D + col] = acc[m][n][rr];
      }
}

// ---------------- launch ----------------
extern "C" void kernel_launch(void* const* d_in, const int* in_sizes, int n_in,
                              void* d_out, int out_size, void* d_ws, size_t ws_size,
                              hipStream_t stream) {
  const float* x  = (const float*)d_in[0];
  const float* w1 = (const float*)d_in[1];
  const float* w2 = (const float*)d_in[2];
  const float* w3 = (const float*)d_in[3];
  const int*   g  = (const int*)d_in[4];

  const int E = in_sizes[4];
  const int D = 4096;
  const int I = 1024;
  const int T = in_sizes[0] / D;

  const size_t szW = (size_t)E * D * I * sizeof(ushort);  // 64 MB
  const size_t szH = (size_t)T * I * sizeof(ushort);      // 64 MB
  const size_t szX = (size_t)T * D * sizeof(ushort);      // 256 MB
  const size_t needSmall = 2 * szW + szH;                 // 192 MB
  const size_t needBig = needSmall + szX;                 // 448 MB
  if (ws_size < needSmall) return;

  char* ws = (char*)d_ws;
  ushort* w1t = (ushort*)ws;              // slot 0 (reused by w2t)
  ushort* w3t = (ushort*)(ws + szW);      // slot 1
  ushort* h   = (ushort*)(ws + 2 * szW);  // slot 2
  ushort* w2t = w1t;
  ushort* xb  = (ushort*)(ws + 2 * szW + szH);  // slot 3 (big path only)

  float* out = (float*)d_out;
  dim3 blk(256);

  k_transpose_bf16<<<dim3(I / 64, D / 64, E), blk, 0, stream>>>(w1, w1t, D, I);
  k_transpose_bf16<<<dim3(I / 64, D / 64, E), blk, 0, stream>>>(w3, w3t, D, I);

  if (ws_size >= needBig) {
    k_f32_to_bf16<<<dim3(2048), blk, 0, stream>>>(x, xb, (size_t)T * D / 4);
    k_gemm1_swiglu64<<<dim3((T / 128) * (I / 64)), blk, 0, stream>>>(xb, w1t, w3t, g, h, T, D, I, E);
  } else {
    k_gemm1_swiglu<<<dim3((T / BM) * (I / BN)), blk, 0, stream>>>(x, w1t, w3t, g, h, T, D, I, E);
  }

  k_transpose_bf16<<<dim3(D / 64, I / 64, E), blk, 0, stream>>>(w2, w2t, I, D);

  k_gemm2<<<dim3((T / BM) * (D / BN)), blk, 0, stream>>>(h, w2t, g, out, T, D, I, E);
}

// Round 4
// 1056.128 us; speedup vs baseline: 1.9168x; 1.3276x over previous
//
#include <hip/hip_runtime.h>
#include <hip/hip_bf16.h>

typedef __attribute__((ext_vector_type(8))) short bf16x8;
typedef __attribute__((ext_vector_type(4))) float f32x4;

#define SBAR() __builtin_amdgcn_sched_barrier(0)
#define WBAR() __builtin_amdgcn_s_barrier()
#define VMC4() asm volatile("s_waitcnt vmcnt(4)" ::: "memory")
#define VMC0() asm volatile("s_waitcnt vmcnt(0)" ::: "memory")

__device__ __forceinline__ ushort f2bf(float f) {
  union { float f; unsigned u; } v; v.f = f;
  unsigned r = v.u + 0x7fffu + ((v.u >> 16) & 1u);
  return (ushort)(r >> 16);
}

__device__ __forceinline__ void gld_lds16(const ushort* gsrc, ushort* lds) {
  __builtin_amdgcn_global_load_lds((const __attribute__((address_space(1))) void*)gsrc,
                                   (__attribute__((address_space(3))) void*)lds, 16, 0, 0);
}

__device__ __forceinline__ f32x4 MF(bf16x8 a, bf16x8 b, f32x4 c) {
  return __builtin_amdgcn_mfma_f32_16x16x32_bf16(a, b, c, 0, 0, 0);
}

// grids are multiples of 8 -> simple bijective XCD swizzle
__device__ __forceinline__ void xcd_map(int bid, int CT, int& r, int& c) {
  const int xcd = bid & 7, j = bid >> 3;
  r = xcd + 8 * (j / CT);
  c = j % CT;
}

__device__ __forceinline__ int expert_of(const int* g, int E, int m0) {
  int e = 0, base = 0;
  while (e < E - 1 && m0 >= base + g[e]) { base += g[e]; ++e; }
  return e;
}

// ================= pack x: [T][D] fp32 -> tiled-A bf16 (RB=256, BK=64, kc-major)
// tile(rt,kt) base = (rt*(D/64)+kt)*16384 ; within: kc*2048 + row*8 + j
__global__ __launch_bounds__(256) void k_pack_x(
    const float* __restrict__ x, ushort* __restrict__ xb, int D) {
  __shared__ ushort sm[256][66];
  const int kt = blockIdx.x;
  const int rt = blockIdx.y;
  const int t = threadIdx.x;
  const int c0 = kt * 64;
  const size_t r0 = (size_t)rt * 256;
#pragma unroll
  for (int p = 0; p < 16; ++p) {
    const int row = p * 16 + (t >> 4);
    const float4 v = *reinterpret_cast<const float4*>(x + (r0 + row) * D + c0 + (t & 15) * 4);
    ushort4 u; u.x = f2bf(v.x); u.y = f2bf(v.y); u.z = f2bf(v.z); u.w = f2bf(v.w);
    *reinterpret_cast<ushort4*>(&sm[row][(t & 15) * 4]) = u;
  }
  __syncthreads();
  ushort* outp = xb + ((size_t)rt * (D >> 6) + kt) * 16384;
#pragma unroll
  for (int p = 0; p < 8; ++p) {
    ushort u[8];
#pragma unroll
    for (int j = 0; j < 8; ++j) u[j] = sm[t][p * 8 + j];
    *reinterpret_cast<uint4*>(outp + p * 2048 + t * 8) = *reinterpret_cast<uint4*>(u);
  }
}

// ================= pack weight: src [E][R(k)][C(n)] fp32 -> tiled-B^T bf16
// rows=C, K=R, row-block RB=1<<rbShift; tile base=((n>>rbShift)*(R/64)+(k/64))*(RB*64)
// within tile: kc*(RB*8) + localrow*8 + (k&7)
__global__ __launch_bounds__(256) void k_pack_w(
    const float* __restrict__ w, ushort* __restrict__ wp, int R, int C, int rbShift) {
  __shared__ ushort sm[64][66];
  const int e = blockIdx.z;
  const size_t mat = (size_t)R * C;
  const float* s = w + (size_t)e * mat;
  ushort* d = wp + (size_t)e * mat;
  const int c0 = blockIdx.x * 64;  // n
  const int r0 = blockIdx.y * 64;  // k
  const int t = threadIdx.x;
#pragma unroll
  for (int p = 0; p < 4; ++p) {
    const int r = p * 16 + (t >> 4);
    const float4 v = *reinterpret_cast<const float4*>(s + (size_t)(r0 + r) * C + c0 + (t & 15) * 4);
    ushort4 u; u.x = f2bf(v.x); u.y = f2bf(v.y); u.z = f2bf(v.z); u.w = f2bf(v.w);
    *reinterpret_cast<ushort4*>(&sm[r][(t & 15) * 4]) = u;
  }
  __syncthreads();
  const int RB = 1 << rbShift;
  const size_t tilebase = ((size_t)(c0 >> rbShift) * (R >> 6) + (r0 >> 6)) * ((size_t)RB * 64);
  const int nbase = c0 & (RB - 1);
#pragma unroll
  for (int p = 0; p < 2; ++p) {
    const int uu = p * 256 + t;
    const int kc = uu >> 6;
    const int rr = uu & 63;
    ushort u[8];
#pragma unroll
    for (int j = 0; j < 8; ++j) u[j] = sm[kc * 8 + j][rr];
    *reinterpret_cast<uint4*>(d + tilebase + (size_t)kc * (RB * 8) + (size_t)(nbase + rr) * 8) =
        *reinterpret_cast<uint4*>(u);
  }
}

// ================= GEMM1: h = silu(x@w1)*(x@w3), 256x(128+128), BK=64, 8-phase
// buf layout (elems): A[0,16384) kc-major 256 rows; B1[16384,24576); B3[24576,32768)
__global__ __launch_bounds__(512, 2) void k_gemm1_8p(
    const ushort* __restrict__ xb, const ushort* __restrict__ w1p,
    const ushort* __restrict__ w3p, const int* __restrict__ g,
    ushort* __restrict__ h, int T, int D, int I, int E) {
  __shared__ ushort lds[2][32768];  // 128 KiB

  const int CT = I >> 7;
  int r, c; xcd_map(blockIdx.x, CT, r, c);
  const int m0 = r << 8, n0 = c << 7;
  const int e = expert_of(g, E, m0);

  const int tid = threadIdx.x;
  const int lane = tid & 63, wave = tid >> 6;
  const int wr = wave >> 2, wc = wave & 3;
  const int l15 = lane & 15, l16 = lane >> 4;

  const int KT = D >> 6;
  const ushort* pA  = xb  + (size_t)r * (D >> 6) * 16384;
  const ushort* pB1 = w1p + (size_t)e * I * D + (size_t)c * (D >> 6) * 8192;
  const ushort* pB3 = w3p + (size_t)e * I * D + (size_t)c * (D >> 6) * 8192;

  const int sto = tid * 8;
  const int aoff  = l16 * 2048 + (wr * 128 + l15) * 8;
  const int b1off = 16384 + l16 * 1024 + (wc * 32 + l15) * 8;
  const int b3off = b1off + 8192;

  const f32x4 zero = {0.f, 0.f, 0.f, 0.f};
  f32x4 acc1[8][2], acc3[8][2];
#pragma unroll
  for (int mi = 0; mi < 8; ++mi)
#pragma unroll
    for (int ni = 0; ni < 2; ++ni) { acc1[mi][ni] = zero; acc3[mi][ni] = zero; }

  // prologue: stage tile 0, issue order = checkpoint order (kh0 first)
  {
    ushort* L = lds[0];
    gld_lds16(pA + sto,          L + sto);
    gld_lds16(pA + 4096 + sto,   L + 4096 + sto);
    gld_lds16(pB1 + sto,         L + 16384 + sto);
    gld_lds16(pB3 + sto,         L + 24576 + sto);
    gld_lds16(pA + 8192 + sto,   L + 8192 + sto);
    gld_lds16(pA + 12288 + sto,  L + 12288 + sto);
    gld_lds16(pB1 + 4096 + sto,  L + 20480 + sto);
    gld_lds16(pB3 + 4096 + sto,  L + 28672 + sto);
  }
  VMC4(); WBAR(); SBAR();

  for (int t = 0; t < KT; ++t) {
    ushort* B = lds[t & 1];
    ushort* N = lds[(t + 1) & 1];
    const bool pf = (t + 1 < KT);
    const ushort* nA  = pA  + (size_t)(t + 1) * 16384;
    const ushort* nB1 = pB1 + (size_t)(t + 1) * 8192;
    const ushort* nB3 = pB3 + (size_t)(t + 1) * 8192;

    bf16x8 af[4], b1f[2], b3f[2];
    // ---- P1: ks=0, mi 0-3 ----
    SBAR();
#pragma unroll
    for (int mi = 0; mi < 4; ++mi) af[mi] = *(const bf16x8*)&B[aoff + mi * 128];
    b1f[0] = *(const bf16x8*)&B[b1off];        b1f[1] = *(const bf16x8*)&B[b1off + 128];
    b3f[0] = *(const bf16x8*)&B[b3off];        b3f[1] = *(const bf16x8*)&B[b3off + 128];
    if (pf) { gld_lds16(nA + sto, N + sto); gld_lds16(nA + 4096 + sto, N + 4096 + sto); }
    SBAR(); WBAR(); SBAR();
    __builtin_amdgcn_s_setprio(1);
#pragma unroll
    for (int mi = 0; mi < 4; ++mi)
#pragma unroll
      for (int ni = 0; ni < 2; ++ni) {
        acc1[mi][ni] = MF(af[mi], b1f[ni], acc1[mi][ni]);
        acc3[mi][ni] = MF(af[mi], b3f[ni], acc3[mi][ni]);
      }
    __builtin_amdgcn_s_setprio(0);
    SBAR(); WBAR();
    // ---- P2: ks=0, mi 4-7 ----
    SBAR();
#pragma unroll
    for (int mi = 0; mi < 4; ++mi) af[mi] = *(const bf16x8*)&B[aoff + (mi + 4) * 128];
    if (pf) { gld_lds16(nB1 + sto, N + 16384 + sto); gld_lds16(nB3 + sto, N + 24576 + sto); }
    SBAR(); WBAR(); SBAR();
    __builtin_amdgcn_s_setprio(1);
#pragma unroll
    for (int mi = 0; mi < 4; ++mi)
#pragma unroll
      for (int ni = 0; ni < 2; ++ni) {
        acc1[mi + 4][ni] = MF(af[mi], b1f[ni], acc1[mi + 4][ni]);
        acc3[mi + 4][ni] = MF(af[mi], b3f[ni], acc3[mi + 4][ni]);
      }
    __builtin_amdgcn_s_setprio(0);
    SBAR();
    if (pf) { VMC4(); } else { VMC0(); }   // gates kh1 of tile t
    WBAR();
    // ---- P3: ks=1, mi 0-3 ----
    SBAR();
#pragma unroll
    for (int mi = 0; mi < 4; ++mi) af[mi] = *(const bf16x8*)&B[aoff + 8192 + mi * 128];
    b1f[0] = *(const bf16x8*)&B[b1off + 4096];  b1f[1] = *(const bf16x8*)&B[b1off + 4096 + 128];
    b3f[0] = *(const bf16x8*)&B[b3off + 4096];  b3f[1] = *(const bf16x8*)&B[b3off + 4096 + 128];
    if (pf) { gld_lds16(nA + 8192 + sto, N + 8192 + sto);
              gld_lds16(nA + 12288 + sto, N + 12288 + sto); }
    SBAR(); WBAR(); SBAR();
    __builtin_amdgcn_s_setprio(1);
#pragma unroll
    for (int mi = 0; mi < 4; ++mi)
#pragma unroll
      for (int ni = 0; ni < 2; ++ni) {
        acc1[mi][ni] = MF(af[mi], b1f[ni], acc1[mi][ni]);
        acc3[mi][ni] = MF(af[mi], b3f[ni], acc3[mi][ni]);
      }
    __builtin_amdgcn_s_setprio(0);
    SBAR(); WBAR();
    // ---- P4: ks=1, mi 4-7 ----
    SBAR();
#pragma unroll
    for (int mi = 0; mi < 4; ++mi) af[mi] = *(const bf16x8*)&B[aoff + 8192 + (mi + 4) * 128];
    if (pf) { gld_lds16(nB1 + 4096 + sto, N + 20480 + sto);
              gld_lds16(nB3 + 4096 + sto, N + 28672 + sto); }
    SBAR(); WBAR(); SBAR();
    __builtin_amdgcn_s_setprio(1);
#pragma unroll
    for (int mi = 0; mi < 4; ++mi)
#pragma unroll
      for (int ni = 0; ni < 2; ++ni) {
        acc1[mi + 4][ni] = MF(af[mi], b1f[ni], acc1[mi + 4][ni]);
        acc3[mi + 4][ni] = MF(af[mi], b3f[ni], acc3[mi + 4][ni]);
      }
    __builtin_amdgcn_s_setprio(0);
    SBAR();
    VMC4();                                 // gates kh0 of tile t+1
    WBAR();
  }

  // epilogue: SwiGLU -> h in tiled-A layout (RB=256, K=I)
#pragma unroll
  for (int mi = 0; mi < 8; ++mi)
#pragma unroll
    for (int ni = 0; ni < 2; ++ni)
#pragma unroll
      for (int rr = 0; rr < 4; ++rr) {
        const float v1 = acc1[mi][ni][rr];
        const float v3 = acc3[mi][ni][rr];
        const float sv = v1 / (1.f + __expf(-v1));
        const int row = m0 + wr * 128 + mi * 16 + l16 * 4 + rr;
        const int col = n0 + wc * 32 + ni * 16 + l15;
        const size_t off = ((size_t)(row >> 8) * (I >> 6) + (col >> 6)) * 16384 +
                           ((col >> 3) & 7) * 2048 + (row & 255) * 8 + (col & 7);
        h[off] = f2bf(sv * v3);
      }
}

// ================= GEMM2: out = h @ w2, 256x256, BK=64, 8-phase, fp32 out
// buf layout: A[0,16384); B[16384,32768)
__global__ __launch_bounds__(512, 2) void k_gemm2_8p(
    const ushort* __restrict__ h, const ushort* __restrict__ w2p,
    const int* __restrict__ g, float* __restrict__ out,
    int T, int D, int I, int E) {
  __shared__ ushort lds[2][32768];

  const int CT = D >> 8;
  int r, cb; xcd_map(blockIdx.x, CT, r, cb);
  const int m0 = r << 8, n0 = cb << 8;
  const int e = expert_of(g, E, m0);

  const int tid = threadIdx.x;
  const int lane = tid & 63, wave = tid >> 6;
  const int wr = wave >> 2, wc = wave & 3;
  const int l15 = lane & 15, l16 = lane >> 4;

  const int KT = I >> 6;
  const ushort* pA = h   + (size_t)r * (I >> 6) * 16384;
  const ushort* pB = w2p + (size_t)e * D * I + (size_t)cb * (I >> 6) * 16384;

  const int sto = tid * 8;
  const int aoff = l16 * 2048 + (wr * 128 + l15) * 8;
  const int boff = 16384 + l16 * 2048 + (wc * 64 + l15) * 8;

  const f32x4 zero = {0.f, 0.f, 0.f, 0.f};
  f32x4 acc[8][4];
#pragma unroll
  for (int mi = 0; mi < 8; ++mi)
#pragma unroll
    for (int ni = 0; ni < 4; ++ni) acc[mi][ni] = zero;

  {
    ushort* L = lds[0];
    gld_lds16(pA + sto,          L + sto);
    gld_lds16(pA + 4096 + sto,   L + 4096 + sto);
    gld_lds16(pB + sto,          L + 16384 + sto);
    gld_lds16(pB + 4096 + sto,   L + 20480 + sto);
    gld_lds16(pA + 8192 + sto,   L + 8192 + sto);
    gld_lds16(pA + 12288 + sto,  L + 12288 + sto);
    gld_lds16(pB + 8192 + sto,   L + 24576 + sto);
    gld_lds16(pB + 12288 + sto,  L + 28672 + sto);
  }
  VMC4(); WBAR(); SBAR();

  for (int t = 0; t < KT; ++t) {
    ushort* B = lds[t & 1];
    ushort* N = lds[(t + 1) & 1];
    const bool pf = (t + 1 < KT);
    const ushort* nA = pA + (size_t)(t + 1) * 16384;
    const ushort* nB = pB + (size_t)(t + 1) * 16384;

    bf16x8 af[4], bf[4];
    // ---- P1: ks=0, mi 0-3 ----
    SBAR();
#pragma unroll
    for (int mi = 0; mi < 4; ++mi) af[mi] = *(const bf16x8*)&B[aoff + mi * 128];
#pragma unroll
    for (int ni = 0; ni < 4; ++ni) bf[ni] = *(const bf16x8*)&B[boff + ni * 128];
    if (pf) { gld_lds16(nA + sto, N + sto); gld_lds16(nA + 4096 + sto, N + 4096 + sto); }
    SBAR(); WBAR(); SBAR();
    __builtin_amdgcn_s_setprio(1);
#pragma unroll
    for (int mi = 0; mi < 4; ++mi)
#pragma unroll
      for (int ni = 0; ni < 4; ++ni) acc[mi][ni] = MF(af[mi], bf[ni], acc[mi][ni]);
    __builtin_amdgcn_s_setprio(0);
    SBAR(); WBAR();
    // ---- P2: ks=0, mi 4-7 ----
    SBAR();
#pragma unroll
    for (int mi = 0; mi < 4; ++mi) af[mi] = *(const bf16x8*)&B[aoff + (mi + 4) * 128];
    if (pf) { gld_lds16(nB + sto, N + 16384 + sto); gld_lds16(nB + 4096 + sto, N + 20480 + sto); }
    SBAR(); WBAR(); SBAR();
    __builtin_amdgcn_s_setprio(1);
#pragma unroll
    for (int mi = 0; mi < 4; ++mi)
#pragma unroll
      for (int ni = 0; ni < 4; ++ni) acc[mi + 4][ni] = MF(af[mi], bf[ni], acc[mi + 4][ni]);
    __builtin_amdgcn_s_setprio(0);
    SBAR();
    if (pf) { VMC4(); } else { VMC0(); }
    WBAR();
    // ---- P3: ks=1, mi 0-3 ----
    SBAR();
#pragma unroll
    for (int mi = 0; mi < 4; ++mi) af[mi] = *(const bf16x8*)&B[aoff + 8192 + mi * 128];
#pragma unroll
    for (int ni = 0; ni < 4; ++ni) bf[ni] = *(const bf16x8*)&B[boff + 8192 + ni * 128];
    if (pf) { gld_lds16(nA + 8192 + sto, N + 8192 + sto);
              gld_lds16(nA + 12288 + sto, N + 12288 + sto); }
    SBAR(); WBAR(); SBAR();
    __builtin_amdgcn_s_setprio(1);
#pragma unroll
    for (int mi = 0; mi < 4; ++mi)
#pragma unroll
      for (int ni = 0; ni < 4; ++ni) acc[mi][ni] = MF(af[mi], bf[ni], acc[mi][ni]);
    __builtin_amdgcn_s_setprio(0);
    SBAR(); WBAR();
    // ---- P4: ks=1, mi 4-7 ----
    SBAR();
#pragma unroll
    for (int mi = 0; mi < 4; ++mi) af[mi] = *(const bf16x8*)&B[aoff + 8192 + (mi + 4) * 128];
    if (pf) { gld_lds16(nB + 8192 + sto, N + 24576 + sto);
              gld_lds16(nB + 12288 + sto, N + 28672 + sto); }
    SBAR(); WBAR(); SBAR();
    __builtin_amdgcn_s_setprio(1);
#pragma unroll
    for (int mi = 0; mi < 4; ++mi)
#pragma unroll
      for (int ni = 0; ni < 4; ++ni) acc[mi + 4][ni] = MF(af[mi], bf[ni], acc[mi + 4][ni]);
    __builtin_amdgcn_s_setprio(0);
    SBAR();
    VMC4();
    WBAR();
  }

#pragma unroll
  for (int mi = 0; mi < 8; ++mi)
#pragma unroll
    for (int ni = 0; ni < 4; ++ni)
#pragma unroll
      for (int rr = 0; rr < 4; ++rr) {
        const int row = m0 + wr * 128 + mi * 16 + l16 * 4 + rr;
        const int col = n0 + wc * 64 + ni * 16 + l15;
        out[(size_t)row * D + col] = acc[mi][ni][rr];
      }
}

// ================= launch =================
extern "C" void kernel_launch(void* const* d_in, const int* in_sizes, int n_in,
                              void* d_out, int out_size, void* d_ws, size_t ws_size,
                              hipStream_t stream) {
  const float* x  = (const float*)d_in[0];
  const float* w1 = (const float*)d_in[1];
  const float* w2 = (const float*)d_in[2];
  const float* w3 = (const float*)d_in[3];
  const int*   g  = (const int*)d_in[4];

  const int E = in_sizes[4];
  const int D = 4096;
  const int I = 1024;
  const int T = in_sizes[0] / D;

  const size_t szW = (size_t)E * D * I * sizeof(ushort);  // 64 MB
  const size_t szH = (size_t)T * I * sizeof(ushort);      // 64 MB
  const size_t szX = (size_t)T * D * sizeof(ushort);      // 256 MB
  const size_t need = 2 * szW + szH + szX;                // 448 MB (verified available in r2/r3)
  if (ws_size < need) return;

  char* ws = (char*)d_ws;
  ushort* w1p = (ushort*)ws;              // slot 0 (reused by w2p after gemm1)
  ushort* w3p = (ushort*)(ws + szW);      // slot 1
  ushort* h   = (ushort*)(ws + 2 * szW);  // slot 2
  ushort* xb  = (ushort*)(ws + 2 * szW + szH);
  ushort* w2p = w1p;

  float* out = (float*)d_out;

  k_pack_w<<<dim3(I / 64, D / 64, E), 256, 0, stream>>>(w1, w1p, D, I, 7);
  k_pack_w<<<dim3(I / 64, D / 64, E), 256, 0, stream>>>(w3, w3p, D, I, 7);
  k_pack_x<<<dim3(D / 64, T / 256), 256, 0, stream>>>(x, xb, D);

  k_gemm1_8p<<<dim3((T / 256) * (I / 128)), 512, 0, stream>>>(xb, w1p, w3p, g, h, T, D, I, E);

  k_pack_w<<<dim3(D / 64, I / 64, E), 256, 0, stream>>>(w2, w2p, I, D, 8);

  k_gemm2_8p<<<dim3((T / 256) * (D / 256)), 512, 0, stream>>>(h, w2p, g, out, T, D, I, E);
}

// Round 5
// 1052.879 us; speedup vs baseline: 1.9227x; 1.0031x over previous
//
#include <hip/hip_runtime.h>
#include <hip/hip_bf16.h>

typedef __attribute__((ext_vector_type(8))) short bf16x8;
typedef __attribute__((ext_vector_type(4))) float f32x4;

#define SBAR() __builtin_amdgcn_sched_barrier(0)
#define WBAR() __builtin_amdgcn_s_barrier()

template<int N> __device__ __forceinline__ void vmcw() {
  if constexpr (N >= 12)     asm volatile("s_waitcnt vmcnt(12)" ::: "memory");
  else if constexpr (N == 8) asm volatile("s_waitcnt vmcnt(8)" ::: "memory");
  else if constexpr (N == 4) asm volatile("s_waitcnt vmcnt(4)" ::: "memory");
  else                       asm volatile("s_waitcnt vmcnt(0)" ::: "memory");
}

__device__ __forceinline__ ushort f2bf(float f) {
  union { float f; unsigned u; } v; v.f = f;
  unsigned r = v.u + 0x7fffu + ((v.u >> 16) & 1u);
  return (ushort)(r >> 16);
}

__device__ __forceinline__ void gld_lds16(const ushort* gsrc, ushort* lds) {
  __builtin_amdgcn_global_load_lds((const __attribute__((address_space(1))) void*)gsrc,
                                   (__attribute__((address_space(3))) void*)lds, 16, 0, 0);
}

__device__ __forceinline__ f32x4 MF(bf16x8 a, bf16x8 b, f32x4 c) {
  return __builtin_amdgcn_mfma_f32_16x16x32_bf16(a, b, c, 0, 0, 0);
}

__device__ __forceinline__ void xcd_map(int bid, int CT, int& r, int& c) {
  const int xcd = bid & 7, j = bid >> 3;
  r = xcd + 8 * (j / CT);
  c = j % CT;
}

__device__ __forceinline__ int expert_of(const int* g, int E, int m0) {
  int e = 0, base = 0;
  while (e < E - 1 && m0 >= base + g[e]) { base += g[e]; ++e; }
  return e;
}

// ================= pack x: [T][D] fp32 -> tiled-A bf16 (RB=256, BK=64, kc-major)
__global__ __launch_bounds__(256) void k_pack_x(
    const float* __restrict__ x, ushort* __restrict__ xb, int D) {
  __shared__ ushort sm[256][66];
  const int kt = blockIdx.x;
  const int rt = blockIdx.y;
  const int t = threadIdx.x;
  const int c0 = kt * 64;
  const size_t r0 = (size_t)rt * 256;
#pragma unroll
  for (int p = 0; p < 16; ++p) {
    const int row = p * 16 + (t >> 4);
    const float4 v = *reinterpret_cast<const float4*>(x + (r0 + row) * D + c0 + (t & 15) * 4);
    ushort4 u; u.x = f2bf(v.x); u.y = f2bf(v.y); u.z = f2bf(v.z); u.w = f2bf(v.w);
    *reinterpret_cast<ushort4*>(&sm[row][(t & 15) * 4]) = u;
  }
  __syncthreads();
  ushort* outp = xb + ((size_t)rt * (D >> 6) + kt) * 16384;
#pragma unroll
  for (int p = 0; p < 8; ++p) {
    ushort u[8];
#pragma unroll
    for (int j = 0; j < 8; ++j) u[j] = sm[t][p * 8 + j];
    *reinterpret_cast<uint4*>(outp + p * 2048 + t * 8) = *reinterpret_cast<uint4*>(u);
  }
}

// ================= pack weight: src [E][R(k)][C(n)] fp32 -> tiled-B^T bf16
__global__ __launch_bounds__(256) void k_pack_w(
    const float* __restrict__ w, ushort* __restrict__ wp, int R, int C, int rbShift) {
  __shared__ ushort sm[64][66];
  const int e = blockIdx.z;
  const size_t mat = (size_t)R * C;
  const float* s = w + (size_t)e * mat;
  ushort* d = wp + (size_t)e * mat;
  const int c0 = blockIdx.x * 64;  // n
  const int r0 = blockIdx.y * 64;  // k
  const int t = threadIdx.x;
#pragma unroll
  for (int p = 0; p < 4; ++p) {
    const int r = p * 16 + (t >> 4);
    const float4 v = *reinterpret_cast<const float4*>(s + (size_t)(r0 + r) * C + c0 + (t & 15) * 4);
    ushort4 u; u.x = f2bf(v.x); u.y = f2bf(v.y); u.z = f2bf(v.z); u.w = f2bf(v.w);
    *reinterpret_cast<ushort4*>(&sm[r][(t & 15) * 4]) = u;
  }
  __syncthreads();
  const int RB = 1 << rbShift;
  const size_t tilebase = ((size_t)(c0 >> rbShift) * (R >> 6) + (r0 >> 6)) * ((size_t)RB * 64);
  const int nbase = c0 & (RB - 1);
#pragma unroll
  for (int p = 0; p < 2; ++p) {
    const int uu = p * 256 + t;
    const int kc = uu >> 6;
    const int rr = uu & 63;
    ushort u[8];
#pragma unroll
    for (int j = 0; j < 8; ++j) u[j] = sm[kc * 8 + j][rr];
    *reinterpret_cast<uint4*>(d + tilebase + (size_t)kc * (RB * 8) + (size_t)(nbase + rr) * 8) =
        *reinterpret_cast<uint4*>(u);
  }
}

// ================= GEMM1 tile body: 4 phases, prefetch distance 2 tiles =================
// buf: A[0,16384) ; B1[16384,24576) ; B3[24576,32768). kh0 = low half of each.
template<bool PF, int C1, int C2>
__device__ __forceinline__ void g1_tile(
    ushort* B, const ushort* nA, const ushort* nB1, const ushort* nB3,
    int sto, int aoff, int b1off, int b3off,
    f32x4 (&acc1)[8][2], f32x4 (&acc3)[8][2]) {
  bf16x8 af[4], b1f[2], b3f[2];
  // ---- P1: kh0, mi 0-3 ----
  SBAR();
#pragma unroll
  for (int mi = 0; mi < 4; ++mi) af[mi] = *(const bf16x8*)&B[aoff + mi * 128];
  b1f[0] = *(const bf16x8*)&B[b1off];       b1f[1] = *(const bf16x8*)&B[b1off + 128];
  b3f[0] = *(const bf16x8*)&B[b3off];       b3f[1] = *(const bf16x8*)&B[b3off + 128];
  SBAR(); WBAR(); SBAR();
  __builtin_amdgcn_s_setprio(1);
#pragma unroll
  for (int mi = 0; mi < 4; ++mi)
#pragma unroll
    for (int ni = 0; ni < 2; ++ni) {
      acc1[mi][ni] = MF(af[mi], b1f[ni], acc1[mi][ni]);
      acc3[mi][ni] = MF(af[mi], b3f[ni], acc3[mi][ni]);
    }
  __builtin_amdgcn_s_setprio(0);
  SBAR(); WBAR();
  // ---- P2: kh0, mi 4-7 ; after mid-barrier, refill kh0 slot with tile t+2 ----
  SBAR();
#pragma unroll
  for (int mi = 0; mi < 4; ++mi) af[mi] = *(const bf16x8*)&B[aoff + (mi + 4) * 128];
  SBAR(); WBAR(); SBAR();
  if (PF) {  // all waves have finished reading kh0 (barrier above) -> WAR-safe
    gld_lds16(nA + sto,         B + sto);
    gld_lds16(nA + 4096 + sto,  B + 4096 + sto);
    gld_lds16(nB1 + sto,        B + 16384 + sto);
    gld_lds16(nB3 + sto,        B + 24576 + sto);
  }
  __builtin_amdgcn_s_setprio(1);
#pragma unroll
  for (int mi = 0; mi < 4; ++mi)
#pragma unroll
    for (int ni = 0; ni < 2; ++ni) {
      acc1[mi + 4][ni] = MF(af[mi], b1f[ni], acc1[mi + 4][ni]);
      acc3[mi + 4][ni] = MF(af[mi], b3f[ni], acc3[mi + 4][ni]);
    }
  __builtin_amdgcn_s_setprio(0);
  SBAR();
  vmcw<C1>();   // gates kh1 of this tile (3 halves of slack remain)
  WBAR();
  // ---- P3: kh1, mi 0-3 ----
  SBAR();
#pragma unroll
  for (int mi = 0; mi < 4; ++mi) af[mi] = *(const bf16x8*)&B[aoff + 8192 + mi * 128];
  b1f[0] = *(const bf16x8*)&B[b1off + 4096]; b1f[1] = *(const bf16x8*)&B[b1off + 4096 + 128];
  b3f[0] = *(const bf16x8*)&B[b3off + 4096]; b3f[1] = *(const bf16x8*)&B[b3off + 4096 + 128];
  SBAR(); WBAR(); SBAR();
  __builtin_amdgcn_s_setprio(1);
#pragma unroll
  for (int mi = 0; mi < 4; ++mi)
#pragma unroll
    for (int ni = 0; ni < 2; ++ni) {
      acc1[mi][ni] = MF(af[mi], b1f[ni], acc1[mi][ni]);
      acc3[mi][ni] = MF(af[mi], b3f[ni], acc3[mi][ni]);
    }
  __builtin_amdgcn_s_setprio(0);
  SBAR(); WBAR();
  // ---- P4: kh1, mi 4-7 ; refill kh1 slot ----
  SBAR();
#pragma unroll
  for (int mi = 0; mi < 4; ++mi) af[mi] = *(const bf16x8*)&B[aoff + 8192 + (mi + 4) * 128];
  SBAR(); WBAR(); SBAR();
  if (PF) {
    gld_lds16(nA + 8192 + sto,   B + 8192 + sto);
    gld_lds16(nA + 12288 + sto,  B + 12288 + sto);
    gld_lds16(nB1 + 4096 + sto,  B + 20480 + sto);
    gld_lds16(nB3 + 4096 + sto,  B + 28672 + sto);
  }
  __builtin_amdgcn_s_setprio(1);
#pragma unroll
  for (int mi = 0; mi < 4; ++mi)
#pragma unroll
    for (int ni = 0; ni < 2; ++ni) {
      acc1[mi + 4][ni] = MF(af[mi], b1f[ni], acc1[mi + 4][ni]);
      acc3[mi + 4][ni] = MF(af[mi], b3f[ni], acc3[mi + 4][ni]);
    }
  __builtin_amdgcn_s_setprio(0);
  SBAR();
  vmcw<C2>();   // gates kh0 of tile t+1
  WBAR();
}

// ================= GEMM1: h = silu(x@w1)*(x@w3), 256x(128+128), BK=64 =================
__global__ __launch_bounds__(512, 2) void k_gemm1_8p(
    const ushort* __restrict__ xb, const ushort* __restrict__ w1p,
    const ushort* __restrict__ w3p, const int* __restrict__ g,
    ushort* __restrict__ h, int T, int D, int I, int E) {
  __shared__ ushort lds[2][32768];  // 128 KiB

  const int CT = I >> 7;
  int r, c; xcd_map(blockIdx.x, CT, r, c);
  const int m0 = r << 8, n0 = c << 7;
  const int e = expert_of(g, E, m0);

  const int tid = threadIdx.x;
  const int lane = tid & 63, wave = tid >> 6;
  const int wr = wave >> 2, wc = wave & 3;
  const int l15 = lane & 15, l16 = lane >> 4;

  const int KT = D >> 6;
  const ushort* pA  = xb  + (size_t)r * (D >> 6) * 16384;
  const ushort* pB1 = w1p + (size_t)e * I * D + (size_t)c * (D >> 6) * 8192;
  const ushort* pB3 = w3p + (size_t)e * I * D + (size_t)c * (D >> 6) * 8192;

  const int sto = tid * 8;
  const int aoff  = l16 * 2048 + (wr * 128 + l15) * 8;
  const int b1off = 16384 + l16 * 1024 + (wc * 32 + l15) * 8;
  const int b3off = b1off + 8192;

  const f32x4 zero = {0.f, 0.f, 0.f, 0.f};
  f32x4 acc1[8][2], acc3[8][2];
#pragma unroll
  for (int mi = 0; mi < 8; ++mi)
#pragma unroll
    for (int ni = 0; ni < 2; ++ni) { acc1[mi][ni] = zero; acc3[mi][ni] = zero; }

  // prologue: stage tiles 0 and 1, half-major issue order
  {
    ushort* L0 = lds[0]; ushort* L1 = lds[1];
    // half0 = kh0(t0)
    gld_lds16(pA + sto,          L0 + sto);
    gld_lds16(pA + 4096 + sto,   L0 + 4096 + sto);
    gld_lds16(pB1 + sto,         L0 + 16384 + sto);
    gld_lds16(pB3 + sto,         L0 + 24576 + sto);
    // half1 = kh1(t0)
    gld_lds16(pA + 8192 + sto,   L0 + 8192 + sto);
    gld_lds16(pA + 12288 + sto,  L0 + 12288 + sto);
    gld_lds16(pB1 + 4096 + sto,  L0 + 20480 + sto);
    gld_lds16(pB3 + 4096 + sto,  L0 + 28672 + sto);
    // half2 = kh0(t1)
    gld_lds16(pA + 16384 + sto,         L1 + sto);
    gld_lds16(pA + 16384 + 4096 + sto,  L1 + 4096 + sto);
    gld_lds16(pB1 + 8192 + sto,         L1 + 16384 + sto);
    gld_lds16(pB3 + 8192 + sto,         L1 + 24576 + sto);
    // half3 = kh1(t1)
    gld_lds16(pA + 16384 + 8192 + sto,  L1 + 8192 + sto);
    gld_lds16(pA + 16384 + 12288 + sto, L1 + 12288 + sto);
    gld_lds16(pB1 + 8192 + 4096 + sto,  L1 + 20480 + sto);
    gld_lds16(pB3 + 8192 + 4096 + sto,  L1 + 28672 + sto);
  }
  vmcw<12>(); WBAR(); SBAR();

  int t = 0;
  for (; t < KT - 2; ++t)
    g1_tile<true, 12, 12>(lds[t & 1], pA + (size_t)(t + 2) * 16384,
                          pB1 + (size_t)(t + 2) * 8192, pB3 + (size_t)(t + 2) * 8192,
                          sto, aoff, b1off, b3off, acc1, acc3);
  g1_tile<false, 8, 4>(lds[t & 1], pA, pB1, pB3, sto, aoff, b1off, b3off, acc1, acc3);
  ++t;
  g1_tile<false, 0, 0>(lds[t & 1], pA, pB1, pB3, sto, aoff, b1off, b3off, acc1, acc3);

  // epilogue: SwiGLU -> h in tiled-A layout (RB=256, K=I)
#pragma unroll
  for (int mi = 0; mi < 8; ++mi)
#pragma unroll
    for (int ni = 0; ni < 2; ++ni)
#pragma unroll
      for (int rr = 0; rr < 4; ++rr) {
        const float v1 = acc1[mi][ni][rr];
        const float v3 = acc3[mi][ni][rr];
        const float sv = v1 / (1.f + __expf(-v1));
        const int row = m0 + wr * 128 + mi * 16 + l16 * 4 + rr;
        const int col = n0 + wc * 32 + ni * 16 + l15;
        const size_t off = ((size_t)(row >> 8) * (I >> 6) + (col >> 6)) * 16384 +
                           ((col >> 3) & 7) * 2048 + (row & 255) * 8 + (col & 7);
        h[off] = f2bf(sv * v3);
      }
}

// ================= GEMM2 tile body =================
// buf: A[0,16384) ; B[16384,32768)
template<bool PF, int C1, int C2>
__device__ __forceinline__ void g2_tile(
    ushort* B, const ushort* nA, const ushort* nB,
    int sto, int aoff, int boff, f32x4 (&acc)[8][4]) {
  bf16x8 af[4], bf[4];
  // ---- P1 ----
  SBAR();
#pragma unroll
  for (int mi = 0; mi < 4; ++mi) af[mi] = *(const bf16x8*)&B[aoff + mi * 128];
#pragma unroll
  for (int ni = 0; ni < 4; ++ni) bf[ni] = *(const bf16x8*)&B[boff + ni * 128];
  SBAR(); WBAR(); SBAR();
  __builtin_amdgcn_s_setprio(1);
#pragma unroll
  for (int mi = 0; mi < 4; ++mi)
#pragma unroll
    for (int ni = 0; ni < 4; ++ni) acc[mi][ni] = MF(af[mi], bf[ni], acc[mi][ni]);
  __builtin_amdgcn_s_setprio(0);
  SBAR(); WBAR();
  // ---- P2 ----
  SBAR();
#pragma unroll
  for (int mi = 0; mi < 4; ++mi) af[mi] = *(const bf16x8*)&B[aoff + (mi + 4) * 128];
  SBAR(); WBAR(); SBAR();
  if (PF) {
    gld_lds16(nA + sto,         B + sto);
    gld_lds16(nA + 4096 + sto,  B + 4096 + sto);
    gld_lds16(nB + sto,         B + 16384 + sto);
    gld_lds16(nB + 4096 + sto,  B + 20480 + sto);
  }
  __builtin_amdgcn_s_setprio(1);
#pragma unroll
  for (int mi = 0; mi < 4; ++mi)
#pragma unroll
    for (int ni = 0; ni < 4; ++ni) acc[mi + 4][ni] = MF(af[mi], bf[ni], acc[mi + 4][ni]);
  __builtin_amdgcn_s_setprio(0);
  SBAR();
  vmcw<C1>();
  WBAR();
  // ---- P3 ----
  SBAR();
#pragma unroll
  for (int mi = 0; mi < 4; ++mi) af[mi] = *(const bf16x8*)&B[aoff + 8192 + mi * 128];
#pragma unroll
  for (int ni = 0; ni < 4; ++ni) bf[ni] = *(const bf16x8*)&B[boff + 8192 + ni * 128];
  SBAR(); WBAR(); SBAR();
  __builtin_amdgcn_s_setprio(1);
#pragma unroll
  for (int mi = 0; mi < 4; ++mi)
#pragma unroll
    for (int ni = 0; ni < 4; ++ni) acc[mi][ni] = MF(af[mi], bf[ni], acc[mi][ni]);
  __builtin_amdgcn_s_setprio(0);
  SBAR(); WBAR();
  // ---- P4 ----
  SBAR();
#pragma unroll
  for (int mi = 0; mi < 4; ++mi) af[mi] = *(const bf16x8*)&B[aoff + 8192 + (mi + 4) * 128];
  SBAR(); WBAR(); SBAR();
  if (PF) {
    gld_lds16(nA + 8192 + sto,   B + 8192 + sto);
    gld_lds16(nA + 12288 + sto,  B + 12288 + sto);
    gld_lds16(nB + 8192 + sto,   B + 24576 + sto);
    gld_lds16(nB + 12288 + sto,  B + 28672 + sto);
  }
  __builtin_amdgcn_s_setprio(1);
#pragma unroll
  for (int mi = 0; mi < 4; ++mi)
#pragma unroll
    for (int ni = 0; ni < 4; ++ni) acc[mi + 4][ni] = MF(af[mi], bf[ni], acc[mi + 4][ni]);
  __builtin_amdgcn_s_setprio(0);
  SBAR();
  vmcw<C2>();
  WBAR();
}

// ================= GEMM2: out = h @ w2, 256x256, BK=64, fp32 out =================
__global__ __launch_bounds__(512, 2) void k_gemm2_8p(
    const ushort* __restrict__ h, const ushort* __restrict__ w2p,
    const int* __restrict__ g, float* __restrict__ out,
    int T, int D, int I, int E) {
  __shared__ ushort lds[2][32768];

  const int CT = D >> 8;
  int r, cb; xcd_map(blockIdx.x, CT, r, cb);
  const int m0 = r << 8, n0 = cb << 8;
  const int e = expert_of(g, E, m0);

  const int tid = threadIdx.x;
  const int lane = tid & 63, wave = tid >> 6;
  const int wr = wave >> 2, wc = wave & 3;
  const int l15 = lane & 15, l16 = lane >> 4;

  const int KT = I >> 6;
  const ushort* pA = h   + (size_t)r * (I >> 6) * 16384;
  const ushort* pB = w2p + (size_t)e * D * I + (size_t)cb * (I >> 6) * 16384;

  const int sto = tid * 8;
  const int aoff = l16 * 2048 + (wr * 128 + l15) * 8;
  const int boff = 16384 + l16 * 2048 + (wc * 64 + l15) * 8;

  const f32x4 zero = {0.f, 0.f, 0.f, 0.f};
  f32x4 acc[8][4];
#pragma unroll
  for (int mi = 0; mi < 8; ++mi)
#pragma unroll
    for (int ni = 0; ni < 4; ++ni) acc[mi][ni] = zero;

  {
    ushort* L0 = lds[0]; ushort* L1 = lds[1];
    // half0
    gld_lds16(pA + sto,          L0 + sto);
    gld_lds16(pA + 4096 + sto,   L0 + 4096 + sto);
    gld_lds16(pB + sto,          L0 + 16384 + sto);
    gld_lds16(pB + 4096 + sto,   L0 + 20480 + sto);
    // half1
    gld_lds16(pA + 8192 + sto,   L0 + 8192 + sto);
    gld_lds16(pA + 12288 + sto,  L0 + 12288 + sto);
    gld_lds16(pB + 8192 + sto,   L0 + 24576 + sto);
    gld_lds16(pB + 12288 + sto,  L0 + 28672 + sto);
    // half2
    gld_lds16(pA + 16384 + sto,          L1 + sto);
    gld_lds16(pA + 16384 + 4096 + sto,   L1 + 4096 + sto);
    gld_lds16(pB + 16384 + sto,          L1 + 16384 + sto);
    gld_lds16(pB + 16384 + 4096 + sto,   L1 + 20480 + sto);
    // half3
    gld_lds16(pA + 16384 + 8192 + sto,   L1 + 8192 + sto);
    gld_lds16(pA + 16384 + 12288 + sto,  L1 + 12288 + sto);
    gld_lds16(pB + 16384 + 8192 + sto,   L1 + 24576 + sto);
    gld_lds16(pB + 16384 + 12288 + sto,  L1 + 28672 + sto);
  }
  vmcw<12>(); WBAR(); SBAR();

  int t = 0;
  for (; t < KT - 2; ++t)
    g2_tile<true, 12, 12>(lds[t & 1], pA + (size_t)(t + 2) * 16384,
                          pB + (size_t)(t + 2) * 16384, sto, aoff, boff, acc);
  g2_tile<false, 8, 4>(lds[t & 1], pA, pB, sto, aoff, boff, acc);
  ++t;
  g2_tile<false, 0, 0>(lds[t & 1], pA, pB, sto, aoff, boff, acc);

#pragma unroll
  for (int mi = 0; mi < 8; ++mi)
#pragma unroll
    for (int ni = 0; ni < 4; ++ni)
#pragma unroll
      for (int rr = 0; rr < 4; ++rr) {
        const int row = m0 + wr * 128 + mi * 16 + l16 * 4 + rr;
        const int col = n0 + wc * 64 + ni * 16 + l15;
        out[(size_t)row * D + col] = acc[mi][ni][rr];
      }
}

// ================= launch =================
extern "C" void kernel_launch(void* const* d_in, const int* in_sizes, int n_in,
                              void* d_out, int out_size, void* d_ws, size_t ws_size,
                              hipStream_t stream) {
  const float* x  = (const float*)d_in[0];
  const float* w1 = (const float*)d_in[1];
  const float* w2 = (const float*)d_in[2];
  const float* w3 = (const float*)d_in[3];
  const int*   g  = (const int*)d_in[4];

  const int E = in_sizes[4];
  const int D = 4096;
  const int I = 1024;
  const int T = in_sizes[0] / D;

  const size_t szW = (size_t)E * D * I * sizeof(ushort);  // 64 MB
  const size_t szH = (size_t)T * I * sizeof(ushort);      // 64 MB
  const size_t szX = (size_t)T * D * sizeof(ushort);      // 256 MB
  const size_t need = 2 * szW + szH + szX;                // 448 MB
  if (ws_size < need) return;

  char* ws = (char*)d_ws;
  ushort* w1p = (ushort*)ws;              // slot 0 (reused by w2p after gemm1)
  ushort* w3p = (ushort*)(ws + szW);      // slot 1
  ushort* h   = (ushort*)(ws + 2 * szW);  // slot 2
  ushort* xb  = (ushort*)(ws + 2 * szW + szH);
  ushort* w2p = w1p;

  float* out = (float*)d_out;

  k_pack_w<<<dim3(I / 64, D / 64, E), 256, 0, stream>>>(w1, w1p, D, I, 7);
  k_pack_w<<<dim3(I / 64, D / 64, E), 256, 0, stream>>>(w3, w3p, D, I, 7);
  k_pack_x<<<dim3(D / 64, T / 256), 256, 0, stream>>>(x, xb, D);

  k_gemm1_8p<<<dim3((T / 256) * (I / 128)), 512, 0, stream>>>(xb, w1p, w3p, g, h, T, D, I, E);

  k_pack_w<<<dim3(D / 64, I / 64, E), 256, 0, stream>>>(w2, w2p, I, D, 8);

  k_gemm2_8p<<<dim3((T / 256) * (D / 256)), 512, 0, stream>>>(h, w2p, g, out, T, D, I, E);
}